// Round 7
// baseline (113.838 us; speedup 1.0000x reference)
//
#include <hip/hip_runtime.h>

// Decoder: 2-layer LSTM (H=32) + MLP (96), B=16384, 25 steps.
// R7: BARRIER-FREE single-wave blocks. One wave owns 16 batch elems and the
// full M (all gates/outputs); cross-phase handoff = LDS + lgkmcnt(0) fence
// (intra-wave, no s_barrier). Weights in VGPR A-frags (~360 VGPR, 1 wave/SIMD,
// launch_bounds(64,1)). Gate weights pre-scaled by log2e (2log2e for g-gate)
// so activations use raw v_exp_f32. Inputs/outputs f32 (R2-proved).

#define PRED 25
#define BATCH 16384
#define SROW 192   // state row (u16): 0..95 x | 96..127 h0 | 128..159 h1 | 160..191 h1lo

typedef unsigned short u16;
typedef unsigned int   u32;
typedef __attribute__((ext_vector_type(8))) short bf16x8;
typedef __attribute__((ext_vector_type(4))) float f32x4;

#define LOG2E  1.44269504088896340736f
#define LOG2E2 2.88539008177792681472f

__device__ __forceinline__ float rcp_(float x){ return __builtin_amdgcn_rcpf(x); }
__device__ __forceinline__ float ex2(float x){ return __builtin_amdgcn_exp2f(x); }
// pre-acts arrive pre-scaled: i/f/o rows by LOG2E, g rows by 2*LOG2E
__device__ __forceinline__ float sigm2(float xp){ return rcp_(1.0f + ex2(-xp)); }
__device__ __forceinline__ float tanh2(float xp){ return 1.0f - 2.0f*rcp_(ex2(xp) + 1.0f); }

__device__ __forceinline__ u16 f2b(float f){
  u32 i = __float_as_uint(f);
  i += 0x7FFFu + ((i >> 16) & 1u);
  return (u16)(i >> 16);
}
__device__ __forceinline__ float b2f(u16 u){ return __uint_as_float(((u32)u) << 16); }

__device__ __forceinline__ int swz(int e, int k){ return e*SROW + (k ^ ((e&7)<<3)); }

#define LGKM_FENCE() asm volatile("s_waitcnt lgkmcnt(0)" ::: "memory")

__device__ __forceinline__ bf16x8 pack8s(const float* src, float s){
  union { bf16x8 v; u16 h[8]; } fr;
  #pragma unroll
  for (int j = 0; j < 8; ++j) fr.h[j] = f2b(src[j]*s);
  return fr.v;
}

extern "C" __global__ __launch_bounds__(64, 1)
void decoder_kernel(const float* __restrict__ obs,  const float* __restrict__ lat,
                    const float* __restrict__ Wfc,  const float* __restrict__ bfc,
                    const float* __restrict__ Wih0, const float* __restrict__ Whh0,
                    const float* __restrict__ bih0, const float* __restrict__ bhh0,
                    const float* __restrict__ Wih1, const float* __restrict__ Whh1,
                    const float* __restrict__ bih1, const float* __restrict__ bhh1,
                    const float* __restrict__ Wmlp, const float* __restrict__ bmlp,
                    float* __restrict__ out)
{
  __shared__ u16 state[16*SROW];
  const int l  = threadIdx.x;
  const int ebase = blockIdx.x * 16;
  const int lr = l & 15;      // e-column for B/C frags; row for A frags
  const int rq = l >> 4;      // k-quad 0..3

  // ---- init x = obs[15] (bf16) ----
  {
    int e = l >> 2, c = (l & 3) * 24;
    const float* src = obs + ((size_t)(15*BATCH) + ebase + e)*96 + c;
    #pragma unroll
    for (int j = 0; j < 12; ++j){
      float2 v = *(const float2*)(src + 2*j);
      u32 pk = (u32)f2b(v.x) | ((u32)f2b(v.y) << 16);
      *(u32*)&state[swz(e, c + 2*j)] = pk;
    }
  }
  // ---- init h0 = h1 = h_init = Wfc@latent + bfc ----
  {
    int u = l >> 1, eh = (l & 1)*8;
    const float* wf = Wfc + u*16;
    float bb = bfc[u];
    #pragma unroll
    for (int r = 0; r < 8; ++r){
      int e = eh + r;
      const float* lp = lat + (size_t)(ebase + e)*16;
      float a = bb;
      #pragma unroll
      for (int j = 0; j < 16; ++j) a = fmaf(wf[j], lp[j], a);
      u16 hb = f2b(a);
      state[swz(e, 96 + u)]  = hb;
      state[swz(e, 128 + u)] = hb;
    }
  }

  // ---- weight A-fragments (full M per wave; gate rows pre-scaled) ----
  bf16x8 aw0[8][4];
  #pragma unroll
  for (int i = 0; i < 8; ++i){
    int vg = i*16 + lr;
    int g  = (vg & 3)*32 + (vg >> 2);       // gate-permuted row
    float s = ((vg & 3) == 2) ? LOG2E2 : LOG2E;
    #pragma unroll
    for (int c = 0; c < 4; ++c){
      int k = c*32 + rq*8;
      const float* src = (k < 96) ? (Wih0 + g*96 + k) : (Whh0 + g*32 + (k - 96));
      aw0[i][c] = pack8s(src, s);
    }
  }
  bf16x8 aw1[8][2];
  #pragma unroll
  for (int i = 0; i < 8; ++i){
    int vg = i*16 + lr;
    int g  = (vg & 3)*32 + (vg >> 2);
    float s = ((vg & 3) == 2) ? LOG2E2 : LOG2E;
    #pragma unroll
    for (int c = 0; c < 2; ++c){
      int k = c*32 + rq*8;
      const float* src = (k < 32) ? (Wih1 + g*32 + k) : (Whh1 + g*32 + (k - 32));
      aw1[i][c] = pack8s(src, s);
    }
  }
  bf16x8 awm[6];
  #pragma unroll
  for (int i = 0; i < 6; ++i){
    int o = i*16 + lr;
    awm[i] = pack8s(Wmlp + o*32 + rq*8, 1.0f);
  }

  // ---- biases (C-frag rows; scaled like their gate rows) ----
  f32x4 b0v[8], b1v[8];
  #pragma unroll
  for (int i = 0; i < 8; ++i){
    int u = i*4 + rq;
    #pragma unroll
    for (int r = 0; r < 4; ++r){
      int g = r*32 + u;
      float s = (r == 2) ? LOG2E2 : LOG2E;
      b0v[i][r] = (bih0[g] + bhh0[g])*s;
      b1v[i][r] = (bih1[g] + bhh1[g])*s;
    }
  }
  f32x4 bmv[6];
  #pragma unroll
  for (int i = 0; i < 6; ++i){
    int o0 = i*16 + rq*4;
    #pragma unroll
    for (int r = 0; r < 4; ++r) bmv[i][r] = bmlp[o0 + r];
  }

  float c0s[8] = {0,0,0,0,0,0,0,0};
  float c1s[8] = {0,0,0,0,0,0,0,0};

  LGKM_FENCE();   // init writes visible to this wave's reads

  #pragma unroll 1
  for (int t = 0; t < PRED; ++t){
    // ---- read current state (x, h0_prev, h1_prev) ----
    bf16x8 bx0  = *(const bf16x8*)&state[swz(lr, 0*32 + rq*8)];
    bf16x8 bx1  = *(const bf16x8*)&state[swz(lr, 1*32 + rq*8)];
    bf16x8 bx2  = *(const bf16x8*)&state[swz(lr, 2*32 + rq*8)];
    bf16x8 bh0p = *(const bf16x8*)&state[swz(lr, 96  + rq*8)];
    bf16x8 bh1p = *(const bf16x8*)&state[swz(lr, 128 + rq*8)];
    // ---- GEMM0: 128 gates x 16 e ----
    f32x4 g0[8];
    #pragma unroll
    for (int i = 0; i < 8; ++i){
      f32x4 a = b0v[i];
      a = __builtin_amdgcn_mfma_f32_16x16x32_bf16(aw0[i][0], bx0,  a, 0, 0, 0);
      a = __builtin_amdgcn_mfma_f32_16x16x32_bf16(aw0[i][1], bx1,  a, 0, 0, 0);
      a = __builtin_amdgcn_mfma_f32_16x16x32_bf16(aw0[i][2], bx2,  a, 0, 0, 0);
      a = __builtin_amdgcn_mfma_f32_16x16x32_bf16(aw0[i][3], bh0p, a, 0, 0, 0);
      g0[i] = a;
    }
    // ---- LSTM0 activation -> h0 ----
    #pragma unroll
    for (int i = 0; i < 8; ++i){
      float ig = sigm2(g0[i][0]);
      float fg = sigm2(g0[i][1]);
      float gg = tanh2(g0[i][2]);
      float og = sigm2(g0[i][3]);
      float cn = fmaf(fg, c0s[i], ig*gg);
      c0s[i] = cn;
      float h = og * tanh2(cn*LOG2E2);
      state[swz(lr, 96 + i*4 + rq)] = f2b(h);
    }
    LGKM_FENCE();
    // ---- GEMM1: [h0_new; h1_prev] ----
    bf16x8 bh0n = *(const bf16x8*)&state[swz(lr, 96 + rq*8)];
    f32x4 g1[8];
    #pragma unroll
    for (int i = 0; i < 8; ++i){
      f32x4 a = b1v[i];
      a = __builtin_amdgcn_mfma_f32_16x16x32_bf16(aw1[i][0], bh0n, a, 0, 0, 0);
      a = __builtin_amdgcn_mfma_f32_16x16x32_bf16(aw1[i][1], bh1p, a, 0, 0, 0);
      g1[i] = a;
    }
    // ---- LSTM1 activation -> h1 (hi) + h1lo (residual) ----
    #pragma unroll
    for (int i = 0; i < 8; ++i){
      float ig = sigm2(g1[i][0]);
      float fg = sigm2(g1[i][1]);
      float gg = tanh2(g1[i][2]);
      float og = sigm2(g1[i][3]);
      float cn = fmaf(fg, c1s[i], ig*gg);
      c1s[i] = cn;
      float h = og * tanh2(cn*LOG2E2);
      u16 hi = f2b(h);
      state[swz(lr, 128 + i*4 + rq)] = hi;
      state[swz(lr, 160 + i*4 + rq)] = f2b(h - b2f(hi));
    }
    LGKM_FENCE();
    // ---- MLP: curr = Wm*(h1_hi + h1_lo) + b; store f32 + bf16 feedback ----
    bf16x8 bmh = *(const bf16x8*)&state[swz(lr, 128 + rq*8)];
    bf16x8 bml = *(const bf16x8*)&state[swz(lr, 160 + rq*8)];
    float* outb = out + (size_t)t*BATCH*96 + (size_t)(ebase + lr)*96;
    #pragma unroll
    for (int i = 0; i < 6; ++i){
      f32x4 a = bmv[i];
      a = __builtin_amdgcn_mfma_f32_16x16x32_bf16(awm[i], bmh, a, 0, 0, 0);
      a = __builtin_amdgcn_mfma_f32_16x16x32_bf16(awm[i], bml, a, 0, 0, 0);
      int o0 = i*16 + rq*4;
      *(f32x4*)(outb + o0) = a;                 // exact f32 output (async)
      u32 p01 = (u32)f2b(a[0]) | ((u32)f2b(a[1]) << 16);
      u32 p23 = (u32)f2b(a[2]) | ((u32)f2b(a[3]) << 16);
      *(u32*)&state[swz(lr, o0)]     = p01;     // bf16 feedback (next x)
      *(u32*)&state[swz(lr, o0 + 2)] = p23;
    }
    LGKM_FENCE();   // x visible before next step's reads
  }
}

extern "C" void kernel_launch(void* const* d_in, const int* in_sizes, int n_in,
                              void* d_out, int out_size, void* d_ws, size_t ws_size,
                              hipStream_t stream){
  decoder_kernel<<<dim3(BATCH/16), dim3(64), 0, stream>>>(
      (const float*)d_in[0],  (const float*)d_in[1],
      (const float*)d_in[3],  (const float*)d_in[4],
      (const float*)d_in[5],  (const float*)d_in[6],
      (const float*)d_in[7],  (const float*)d_in[8],
      (const float*)d_in[9],  (const float*)d_in[10],
      (const float*)d_in[11], (const float*)d_in[12],
      (const float*)d_in[13], (const float*)d_in[14],
      (float*)d_out);
}

// Round 8
// 78.762 us; speedup vs baseline: 1.4453x; 1.4453x over previous
//
#include <hip/hip_runtime.h>

// Decoder: 2-layer LSTM (H=32) + MLP (96), B=16384, 25 steps.
// R8 = R6 structure (2-wave blocks, m-split, 3 barriers/step) + DUAL-STREAM:
// each block owns two independent 16-elem streams; same-phase work doubles ->
// compiler-scheduled ILP fills the serial-dependency stalls R6 measured
// (8700cyc/step vs ~1750 issue). Weights shared across streams. exp2-prescale
// from R7 (numerics proved). Inputs/outputs f32 (R2-proved).

#define PRED 25
#define BATCH 16384
#define ET    32    // 2 streams x 16
#define XROW  192   // xh row (u16): 0..95 x/curr, 96..127 h0_A, 128..159 h0_B
#define HROW  128   // hh row: 0..31 h0, 32..63 h1_A, 64..95 h1_B
#define LROW  64    // h1lo row

typedef unsigned short u16;
typedef unsigned int   u32;
typedef __attribute__((ext_vector_type(8))) short bf16x8;
typedef __attribute__((ext_vector_type(4))) float f32x4;

#define LOG2E  1.44269504088896340736f
#define LOG2E2 2.88539008177792681472f

__device__ __forceinline__ float rcp_(float x){ return __builtin_amdgcn_rcpf(x); }
__device__ __forceinline__ float ex2(float x){ return __builtin_amdgcn_exp2f(x); }
// pre-acts pre-scaled: i/f/o rows by LOG2E, g rows by 2*LOG2E
__device__ __forceinline__ float sigm2(float xp){ return rcp_(1.0f + ex2(-xp)); }
__device__ __forceinline__ float tanh2(float xp){ return 1.0f - 2.0f*rcp_(ex2(xp) + 1.0f); }

__device__ __forceinline__ u16 f2b(float f){
  u32 i = __float_as_uint(f);
  i += 0x7FFFu + ((i >> 16) & 1u);
  return (u16)(i >> 16);
}
__device__ __forceinline__ float b2f(u16 u){ return __uint_as_float(((u32)u) << 16); }

struct __align__(16) SM {
  u16 xh[2][16*XROW];
  u16 hh[2][16*HROW];
  u16 h1lo[2][16*LROW];
};

__device__ __forceinline__ int swx(int e, int k){ return e*XROW + (k ^ ((e&7)<<3)); }
__device__ __forceinline__ int swh(int e, int k){ return e*HROW + (k ^ ((e&7)<<3)); }
__device__ __forceinline__ int swl(int e, int k){ return e*LROW + (k ^ ((e&7)<<3)); }

__device__ __forceinline__ bf16x8 pack8s(const float* src, float s){
  union { bf16x8 v; u16 h[8]; } fr;
  #pragma unroll
  for (int j = 0; j < 8; ++j) fr.h[j] = f2b(src[j]*s);
  return fr.v;
}

extern "C" __global__ __launch_bounds__(128, 1)
void decoder_kernel(const float* __restrict__ obs,  const float* __restrict__ lat,
                    const float* __restrict__ Wfc,  const float* __restrict__ bfc,
                    const float* __restrict__ Wih0, const float* __restrict__ Whh0,
                    const float* __restrict__ bih0, const float* __restrict__ bhh0,
                    const float* __restrict__ Wih1, const float* __restrict__ Whh1,
                    const float* __restrict__ bih1, const float* __restrict__ bhh1,
                    const float* __restrict__ Wmlp, const float* __restrict__ bmlp,
                    float* __restrict__ out)
{
  __shared__ SM sm;
  const int tid = threadIdx.x;
  const int ebase = blockIdx.x * ET;
  const int mh = tid >> 6;        // wave 0..1 = m-half
  const int l  = tid & 63;
  const int lr = l & 15;          // row/col in 16-tile; e within stream
  const int kq = l >> 4;          // k-quad 0..3

  // ---- one-time LDS init: x = obs[15] (bf16), h_init -> h0/h1 parity 0 ----
  {
    int e = tid >> 2, c0 = (tid & 3)*24;
    int s = e >> 4, er = e & 15;
    const float* src = obs + ((size_t)(15*BATCH) + ebase + e)*96 + c0;
    #pragma unroll
    for (int j = 0; j < 12; ++j){
      float2 v = *(const float2*)(src + 2*j);
      u32 pk = (u32)f2b(v.x) | ((u32)f2b(v.y) << 16);
      *(u32*)&sm.xh[s][swx(er, c0 + 2*j)] = pk;
    }
  }
  {
    int u = tid & 31, e8 = (tid >> 5)*8;
    const float* wf = Wfc + u*16;
    float bb = bfc[u];
    #pragma unroll
    for (int r = 0; r < 8; ++r){
      int e = e8 + r, s = e >> 4, er = e & 15;
      const float* lp = lat + (size_t)(ebase + e)*16;
      float a = bb;
      #pragma unroll
      for (int j = 0; j < 16; ++j) a = fmaf(wf[j], lp[j], a);
      u16 hb = f2b(a);
      sm.xh[s][swx(er, 96 + u)] = hb;   // h0 parity 0
      sm.hh[s][swh(er, 32 + u)] = hb;   // h1 parity 0
    }
  }

  // ---- preload weight A-fragments (step-invariant; gate rows pre-scaled) ----
  bf16x8 aw0[4][4];                 // GEMM0: 4 m-tiles x 4 k-chunks
  #pragma unroll
  for (int i = 0; i < 4; ++i){
    int vg = (mh*4 + i)*16 + lr;
    int g  = (vg & 3)*32 + (vg >> 2);     // gate-permuted row
    float sc = ((vg & 3) == 2) ? LOG2E2 : LOG2E;
    #pragma unroll
    for (int c = 0; c < 4; ++c){
      int k = c*32 + kq*8;
      const float* src = (k < 96) ? (Wih0 + g*96 + k) : (Whh0 + g*32 + (k - 96));
      aw0[i][c] = pack8s(src, sc);
    }
  }
  bf16x8 aw1[4][2];                 // GEMM1: K=64
  #pragma unroll
  for (int i = 0; i < 4; ++i){
    int vg = (mh*4 + i)*16 + lr;
    int g  = (vg & 3)*32 + (vg >> 2);
    float sc = ((vg & 3) == 2) ? LOG2E2 : LOG2E;
    #pragma unroll
    for (int c = 0; c < 2; ++c){
      int k = c*32 + kq*8;
      const float* src = (k < 32) ? (Wih1 + g*32 + k) : (Whh1 + g*32 + (k - 32));
      aw1[i][c] = pack8s(src, sc);
    }
  }
  bf16x8 awm[3];                    // MLP: 3 m-tiles per wave, K=32
  #pragma unroll
  for (int i = 0; i < 3; ++i){
    int o = (mh*3 + i)*16 + lr;
    awm[i] = pack8s(Wmlp + o*32 + kq*8, 1.0f);
  }

  // ---- biases (C-frag rows = kq*4 + r; scaled like their gate rows) ----
  f32x4 bias0v[4], bias1v[4];
  #pragma unroll
  for (int i = 0; i < 4; ++i){
    int u = (mh*4 + i)*4 + kq;
    #pragma unroll
    for (int r = 0; r < 4; ++r){
      int g = r*32 + u;
      float sc = (r == 2) ? LOG2E2 : LOG2E;
      bias0v[i][r] = (bih0[g] + bhh0[g])*sc;
      bias1v[i][r] = (bih1[g] + bhh1[g])*sc;
    }
  }
  f32x4 biasmv[3];
  #pragma unroll
  for (int i = 0; i < 3; ++i){
    int o0 = (mh*3 + i)*16 + kq*4;
    #pragma unroll
    for (int r = 0; r < 4; ++r) biasmv[i][r] = bmlp[o0 + r];
  }

  float c0s[2][4] = {{0,0,0,0},{0,0,0,0}};
  float c1s[2][4] = {{0,0,0,0},{0,0,0,0}};

  __syncthreads();

  f32x4 am[2][3];    // MLP results, stored to global AFTER B5

  for (int t = 0; t < PRED; ++t){
    const int p = t & 1;
    // ---- P1: GEMM0 both streams (independent -> ILP) ----
    f32x4 g0[2][4];
    #pragma unroll
    for (int s = 0; s < 2; ++s){
      bf16x8 bx0 = *(const bf16x8*)&sm.xh[s][swx(lr, 0*32 + kq*8)];
      bf16x8 bx1 = *(const bf16x8*)&sm.xh[s][swx(lr, 1*32 + kq*8)];
      bf16x8 bx2 = *(const bf16x8*)&sm.xh[s][swx(lr, 2*32 + kq*8)];
      bf16x8 bx3 = *(const bf16x8*)&sm.xh[s][swx(lr, 96 + 32*p + kq*8)];
      #pragma unroll
      for (int i = 0; i < 4; ++i){
        f32x4 a = bias0v[i];
        a = __builtin_amdgcn_mfma_f32_16x16x32_bf16(aw0[i][0], bx0, a, 0, 0, 0);
        a = __builtin_amdgcn_mfma_f32_16x16x32_bf16(aw0[i][1], bx1, a, 0, 0, 0);
        a = __builtin_amdgcn_mfma_f32_16x16x32_bf16(aw0[i][2], bx2, a, 0, 0, 0);
        a = __builtin_amdgcn_mfma_f32_16x16x32_bf16(aw0[i][3], bx3, a, 0, 0, 0);
        g0[s][i] = a;
      }
    }
    // ---- LSTM0 activation; h0 -> xh parity p^1 + hh rows 0..31 ----
    #pragma unroll
    for (int s = 0; s < 2; ++s)
      #pragma unroll
      for (int i = 0; i < 4; ++i){
        float ig = sigm2(g0[s][i][0]);
        float fg = sigm2(g0[s][i][1]);
        float gg = tanh2(g0[s][i][2]);
        float og = sigm2(g0[s][i][3]);
        float cn = fmaf(fg, c0s[s][i], ig*gg);
        c0s[s][i] = cn;
        u16 hb = f2b(og * tanh2(cn*LOG2E2));
        int u = (mh*4 + i)*4 + kq;
        sm.xh[s][swx(lr, 96 + 32*(p^1) + u)] = hb;
        sm.hh[s][swh(lr, u)] = hb;
      }
    __syncthreads();   // B2: h0 visible (also drains prev-step stores)
    // ---- P3: GEMM1 both streams ----
    f32x4 g1[2][4];
    #pragma unroll
    for (int s = 0; s < 2; ++s){
      bf16x8 bh0 = *(const bf16x8*)&sm.hh[s][swh(lr, kq*8)];
      bf16x8 bh1 = *(const bf16x8*)&sm.hh[s][swh(lr, 32 + 32*p + kq*8)];
      #pragma unroll
      for (int i = 0; i < 4; ++i){
        f32x4 a = bias1v[i];
        a = __builtin_amdgcn_mfma_f32_16x16x32_bf16(aw1[i][0], bh0, a, 0, 0, 0);
        a = __builtin_amdgcn_mfma_f32_16x16x32_bf16(aw1[i][1], bh1, a, 0, 0, 0);
        g1[s][i] = a;
      }
    }
    #pragma unroll
    for (int s = 0; s < 2; ++s)
      #pragma unroll
      for (int i = 0; i < 4; ++i){
        float ig = sigm2(g1[s][i][0]);
        float fg = sigm2(g1[s][i][1]);
        float gg = tanh2(g1[s][i][2]);
        float og = sigm2(g1[s][i][3]);
        float cn = fmaf(fg, c1s[s][i], ig*gg);
        c1s[s][i] = cn;
        float h1 = og * tanh2(cn*LOG2E2);
        u16 hi = f2b(h1);
        u16 lo = f2b(h1 - b2f(hi));
        int u = (mh*4 + i)*4 + kq;
        sm.hh[s][swh(lr, 32 + 32*(p^1) + u)] = hi;   // h1_new
        sm.h1lo[s][swl(lr, u)] = lo;                 // residual for MLP split
      }
    __syncthreads();   // B4: h1 visible
    // ---- P4: MLP both streams; bf16 feedback to xh; f32 result deferred ----
    #pragma unroll
    for (int s = 0; s < 2; ++s){
      bf16x8 bmh = *(const bf16x8*)&sm.hh[s][swh(lr, 32 + 32*(p^1) + kq*8)];
      bf16x8 bml = *(const bf16x8*)&sm.h1lo[s][swl(lr, kq*8)];
      #pragma unroll
      for (int i = 0; i < 3; ++i){
        f32x4 a = biasmv[i];
        a = __builtin_amdgcn_mfma_f32_16x16x32_bf16(awm[i], bmh, a, 0, 0, 0);
        a = __builtin_amdgcn_mfma_f32_16x16x32_bf16(awm[i], bml, a, 0, 0, 0);
        am[s][i] = a;
        int o0 = (mh*3 + i)*16 + kq*4;
        u32 pk01 = (u32)f2b(a[0]) | ((u32)f2b(a[1]) << 16);
        u32 pk23 = (u32)f2b(a[2]) | ((u32)f2b(a[3]) << 16);
        *(u32*)&sm.xh[s][swx(lr, o0)]     = pk01;   // next step's x
        *(u32*)&sm.xh[s][swx(lr, o0 + 2)] = pk23;
      }
    }
    __syncthreads();   // B5: next x visible for P1(t+1)
    // ---- global stores AFTER barrier: ack overlaps next P1 ----
    #pragma unroll
    for (int s = 0; s < 2; ++s){
      float* outb = out + (size_t)t*BATCH*96 + (size_t)(ebase + s*16 + lr)*96;
      #pragma unroll
      for (int i = 0; i < 3; ++i){
        int o0 = (mh*3 + i)*16 + kq*4;
        *(f32x4*)(outb + o0) = am[s][i];
      }
    }
  }
}

extern "C" void kernel_launch(void* const* d_in, const int* in_sizes, int n_in,
                              void* d_out, int out_size, void* d_ws, size_t ws_size,
                              hipStream_t stream){
  decoder_kernel<<<dim3(BATCH/ET), dim3(128), 0, stream>>>(
      (const float*)d_in[0],  (const float*)d_in[1],
      (const float*)d_in[3],  (const float*)d_in[4],
      (const float*)d_in[5],  (const float*)d_in[6],
      (const float*)d_in[7],  (const float*)d_in[8],
      (const float*)d_in[9],  (const float*)d_in[10],
      (const float*)d_in[11], (const float*)d_in[12],
      (const float*)d_in[13], (const float*)d_in[14],
      (float*)d_out);
}